// Round 2
// baseline (407.669 us; speedup 1.0000x reference)
//
#include <hip/hip_runtime.h>
#include <hip/hip_bf16.h>
#include <math.h>

#define NQ 14
#define DIM 16384
#define NB 256
#define NH 1024

// LDS swizzle for the state arrays: i + 5*(i>>5)  (injective, <=2-way banks)
#define SW(i) ((i) + 5 * ((i) >> 5))
#define SW_SIZE (DIM + 5 * (DIM / 32))   // 16384 + 2560 = 18944

// ---------------------------------------------------------------- kernel A
// params = x @ w_pre^T + b_pre ; v[b][q] = (cos(th/2), 0, cos(phi)sin, sin(phi)sin)
__global__ __launch_bounds__(256) void k_pre(const float* __restrict__ x,
                                             const float* __restrict__ w_pre,
                                             const float* __restrict__ b_pre,
                                             float* __restrict__ v_buf) {
    int b = blockIdx.x;
    int t = threadIdx.x;
    __shared__ float red[28][4];

    float4 xs = ((const float4*)(x + (size_t)b * NH))[t];
    float acc[28];
#pragma unroll
    for (int j = 0; j < 28; j++) {
        float4 w = ((const float4*)(w_pre + (size_t)j * NH))[t];
        acc[j] = xs.x * w.x + xs.y * w.y + xs.z * w.z + xs.w * w.w;
    }
    int lane = t & 63, wv = t >> 6;
#pragma unroll
    for (int j = 0; j < 28; j++) {
        float a = acc[j];
#pragma unroll
        for (int o = 32; o > 0; o >>= 1) a += __shfl_down(a, o);
        if (lane == 0) red[j][wv] = a;
    }
    __syncthreads();
    if (t < NQ) {
        float p0 = red[2*t][0] + red[2*t][1] + red[2*t][2] + red[2*t][3] + b_pre[2*t];
        float p1 = red[2*t+1][0] + red[2*t+1][1] + red[2*t+1][2] + red[2*t+1][3] + b_pre[2*t+1];
        float c = cosf(p0 * 0.5f), s = sinf(p0 * 0.5f);
        float cp = cosf(p1), sp = sinf(p1);
        ((float4*)v_buf)[b * NQ + t] = make_float4(c, 0.f, cp * s, sp * s);
    }
}

// ---------------------------------------------------------------- kernel B
// Gram-Schmidt QR (double) -> Q with positive-real diag(R) == make_unitary(M)
template <int N>
__device__ void gs_qr(const float* Mre, const float* Mim, float* Uout) {
    double qre[N][N], qim[N][N];   // [col][row]
#pragma unroll
    for (int j = 0; j < N; j++) {
        double vr[N], vi[N];
#pragma unroll
        for (int r = 0; r < N; r++) { vr[r] = (double)Mre[r * N + j]; vi[r] = (double)Mim[r * N + j]; }
#pragma unroll
        for (int i = 0; i < N; i++) {
            if (i < j) {
                double rr = 0.0, ri = 0.0;
#pragma unroll
                for (int r = 0; r < N; r++) {
                    rr += qre[i][r] * vr[r] + qim[i][r] * vi[r];
                    ri += qre[i][r] * vi[r] - qim[i][r] * vr[r];
                }
#pragma unroll
                for (int r = 0; r < N; r++) {
                    vr[r] -= rr * qre[i][r] - ri * qim[i][r];
                    vi[r] -= rr * qim[i][r] + ri * qre[i][r];
                }
            }
        }
        double nn = 0.0;
#pragma unroll
        for (int r = 0; r < N; r++) nn += vr[r] * vr[r] + vi[r] * vi[r];
        double inv = 1.0 / sqrt(nn);
#pragma unroll
        for (int r = 0; r < N; r++) { qre[j][r] = vr[r] * inv; qim[j][r] = vi[r] * inv; }
    }
#pragma unroll
    for (int r = 0; r < N; r++)
#pragma unroll
        for (int j = 0; j < N; j++) {
            Uout[(r * N + j) * 2]     = (float)qre[j][r];
            Uout[(r * N + j) * 2 + 1] = (float)qim[j][r];
        }
}

__global__ void k_qr(const float* __restrict__ sq_re, const float* __restrict__ sq_im,
                     const float* __restrict__ ent_re, const float* __restrict__ ent_im,
                     float* __restrict__ sqU, float* __restrict__ entU) {
    int t = threadIdx.x;
    if (t < NQ) {
        gs_qr<2>(sq_re + t * 4, sq_im + t * 4, sqU + t * 8);
    } else if (t < NQ + (NQ - 1)) {
        int e = t - NQ;
        gs_qr<4>(ent_re + e * 16, ent_im + e * 16, entU + e * 32);
    }
}

// ---------------------------------------------------------------- kernel C
// Per batch row: build state = prod_q (U_q v_q) directly (1q gates fused into
// the product), apply 13 two-qubit gates in LDS, write probs.
extern __shared__ float smem[];
__global__ __launch_bounds__(1024) void k_state(const float* __restrict__ v_buf,
                                                const float* __restrict__ sqU,
                                                const float* __restrict__ entU,
                                                float* __restrict__ probs) {
    const int b = blockIdx.x, t = threadIdx.x;
    float* sre  = smem;                       // SW_SIZE
    float* simg = smem + SW_SIZE;             // SW_SIZE
    float* wloc = smem + 2 * SW_SIZE;         // 14*4
    float* g2   = wloc + NQ * 4;              // 13*32
    float* hi   = g2 + (NQ - 1) * 32;         // 16*2

    if (t < (NQ - 1) * 32) g2[t] = entU[t];
    if (t < NQ) {
        // w_q = U_q v_q  (fused single-qubit gates)
        float4 v = ((const float4*)v_buf)[b * NQ + t];
        const float* u = sqU + t * 8;
        float w0r = u[0]*v.x - u[1]*v.y + u[2]*v.z - u[3]*v.w;
        float w0i = u[0]*v.y + u[1]*v.x + u[2]*v.w + u[3]*v.z;
        float w1r = u[4]*v.x - u[5]*v.y + u[6]*v.z - u[7]*v.w;
        float w1i = u[4]*v.y + u[5]*v.x + u[6]*v.w + u[7]*v.z;
        wloc[t*4+0] = w0r; wloc[t*4+1] = w0i; wloc[t*4+2] = w1r; wloc[t*4+3] = w1i;
    }
    __syncthreads();
    if (t < 16) {   // product over qubits 10..13 (index bits 10..13 = k)
        float hr = 1.f, hii = 0.f;
#pragma unroll
        for (int q = 10; q < 14; q++) {
            int bit = (t >> (q - 10)) & 1;
            float br = wloc[q*4 + 2*bit], bi = wloc[q*4 + 2*bit + 1];
            float nr = hr*br - hii*bi, ni = hr*bi + hii*br;
            hr = nr; hii = ni;
        }
        hi[2*t] = hr; hi[2*t+1] = hii;
    }
    __syncthreads();
    {   // product over qubits 0..9 (index bits 0..9 = t)
        float lr = 1.f, li = 0.f;
#pragma unroll
        for (int q = 0; q < 10; q++) {
            int bit = (t >> q) & 1;
            float br = wloc[q*4 + 2*bit], bi = wloc[q*4 + 2*bit + 1];
            float nr = lr*br - li*bi, ni = lr*bi + li*br;
            lr = nr; li = ni;
        }
#pragma unroll
        for (int k = 0; k < 16; k++) {
            int idx = k * 1024 + t;
            float hr = hi[2*k], hii = hi[2*k+1];
            sre[SW(idx)]  = lr*hr - li*hii;
            simg[SW(idx)] = lr*hii + li*hr;
        }
    }
    __syncthreads();

    // 13 two-qubit gates on (q, q+1); matrix row = 2*bit_{q+1} + bit_q,
    // amplitude offset of matrix index m is base + (m<<q).
    for (int e = 0; e < NQ - 1; e++) {
        float gr[4][4], gi[4][4];
#pragma unroll
        for (int m = 0; m < 16; m++) {
            gr[m >> 2][m & 3] = g2[e*32 + 2*m];
            gi[m >> 2][m & 3] = g2[e*32 + 2*m + 1];
        }
        const int q = e, mask = (1 << q) - 1;
#pragma unroll
        for (int k = 0; k < 4; k++) {
            int g = k * 1024 + t;
            int base = ((g & ~mask) << 2) | (g & mask);
            int ia[4];
#pragma unroll
            for (int m = 0; m < 4; m++) ia[m] = SW(base + (m << q));
            float ar[4], ai[4];
#pragma unroll
            for (int m = 0; m < 4; m++) { ar[m] = sre[ia[m]]; ai[m] = simg[ia[m]]; }
            float orr[4], oii[4];
#pragma unroll
            for (int r = 0; r < 4; r++) {
                float nr = 0.f, ni = 0.f;
#pragma unroll
                for (int c = 0; c < 4; c++) {
                    nr += gr[r][c] * ar[c] - gi[r][c] * ai[c];
                    ni += gr[r][c] * ai[c] + gi[r][c] * ar[c];
                }
                orr[r] = nr; oii[r] = ni;
            }
#pragma unroll
            for (int r = 0; r < 4; r++) { sre[ia[r]] = orr[r]; simg[ia[r]] = oii[r]; }
        }
        __syncthreads();
    }

#pragma unroll
    for (int k = 0; k < 16; k++) {
        int idx = k * 1024 + t;
        float r = sre[SW(idx)], i2 = simg[SW(idx)];
        probs[(size_t)b * DIM + idx] = r * r + i2 * i2;
    }
}

// ---------------------------------------------------------------- kernel D
// partial[z] = probs[64 rows] @ w_post[64 rows]^T over K-range z
#define SPLITK 8
__global__ __launch_bounds__(256) void k_gemm(const float* __restrict__ A,
                                              const float* __restrict__ Bw,
                                              float* __restrict__ part) {
    __shared__ float As[64 * 64];
    __shared__ float Bs[64 * 64];
    const int t = threadIdx.x;
    const int bm0 = blockIdx.x * 64;
    const int hn0 = blockIdx.y * 64;
    const int k0  = blockIdx.z * (DIM / SPLITK);
    const int lr = t >> 4;           // 0..15 (load row group)
    const int lc = (t & 15) * 4;     // 0..60 (load col*4)
    const int ty = t >> 4, tx = t & 15;
    float acc[4][4] = {};

    for (int kc = 0; kc < DIM / SPLITK; kc += 64) {
#pragma unroll
        for (int j = 0; j < 4; j++) {
            int r = lr + 16 * j;
            int sc = lc ^ ((r & 7) << 2);
            float4 av = *(const float4*)(A  + (size_t)(bm0 + r) * DIM + k0 + kc + lc);
            float4 bv = *(const float4*)(Bw + (size_t)(hn0 + r) * DIM + k0 + kc + lc);
            *(float4*)&As[r * 64 + sc] = av;
            *(float4*)&Bs[r * 64 + sc] = bv;
        }
        __syncthreads();
#pragma unroll
        for (int kk = 0; kk < 64; kk += 4) {
            float4 a[4], bb[4];
#pragma unroll
            for (int i = 0; i < 4; i++) {
                int r = ty + 16 * i;
                a[i] = *(const float4*)&As[r * 64 + (kk ^ ((r & 7) << 2))];
            }
#pragma unroll
            for (int j = 0; j < 4; j++) {
                int r = tx + 16 * j;
                bb[j] = *(const float4*)&Bs[r * 64 + (kk ^ ((r & 7) << 2))];
            }
#pragma unroll
            for (int i = 0; i < 4; i++)
#pragma unroll
                for (int j = 0; j < 4; j++)
                    acc[i][j] += a[i].x * bb[j].x + a[i].y * bb[j].y +
                                 a[i].z * bb[j].z + a[i].w * bb[j].w;
        }
        __syncthreads();
    }
#pragma unroll
    for (int i = 0; i < 4; i++)
#pragma unroll
        for (int j = 0; j < 4; j++)
            part[(size_t)blockIdx.z * (NB * NH) +
                 (size_t)(bm0 + ty + 16 * i) * NH + hn0 + tx + 16 * j] = acc[i][j];
}

__global__ __launch_bounds__(256) void k_reduce(const float* __restrict__ part,
                                                const float* __restrict__ b_post,
                                                float* __restrict__ out) {
    int i = blockIdx.x * 256 + threadIdx.x;   // 0..262143
    float s = b_post[i & (NH - 1)];
#pragma unroll
    for (int z = 0; z < SPLITK; z++) s += part[(size_t)z * (NB * NH) + i];
    out[i] = s;
}

// ---------------------------------------------------------------- launch
extern "C" void kernel_launch(void* const* d_in, const int* in_sizes, int n_in,
                              void* d_out, int out_size, void* d_ws, size_t ws_size,
                              hipStream_t stream) {
    const float* x      = (const float*)d_in[0];
    const float* w_pre  = (const float*)d_in[1];
    const float* b_pre  = (const float*)d_in[2];
    const float* w_post = (const float*)d_in[3];
    const float* b_post = (const float*)d_in[4];
    const float* sq_re  = (const float*)d_in[5];
    const float* sq_im  = (const float*)d_in[6];
    const float* ent_re = (const float*)d_in[7];
    const float* ent_im = (const float*)d_in[8];
    float* out = (float*)d_out;
    float* ws  = (float*)d_ws;

    float* v_buf = ws;                       // 256*14*4 = 14336 floats
    float* sqU   = ws + 14336;               // 112
    float* entU  = ws + 14448;               // 416
    float* probs = ws + 14864;               // 4194304 (16 MB)
    float* part  = ws + 14864 + (size_t)NB * DIM;   // 8*256*1024 = 2097152 (8 MB)

    k_pre<<<NB, 256, 0, stream>>>(x, w_pre, b_pre, v_buf);
    k_qr<<<1, 64, 0, stream>>>(sq_re, sq_im, ent_re, ent_im, sqU, entU);

    const int smem_bytes = (2 * SW_SIZE + NQ * 4 + (NQ - 1) * 32 + 32) * 4;
    (void)hipFuncSetAttribute((const void*)k_state,
                              hipFuncAttributeMaxDynamicSharedMemorySize, smem_bytes);
    k_state<<<NB, 1024, smem_bytes, stream>>>(v_buf, sqU, entU, probs);

    k_gemm<<<dim3(NB / 64, NH / 64, SPLITK), 256, 0, stream>>>(probs, w_post, part);
    k_reduce<<<(NB * NH) / 256, 256, 0, stream>>>(part, b_post, out);
}

// Round 3
// 206.486 us; speedup vs baseline: 1.9743x; 1.9743x over previous
//
#include <hip/hip_runtime.h>
#include <hip/hip_bf16.h>
#include <math.h>

#define NQ 14
#define DIM 16384
#define NB 256
#define NH 1024
#define SPLITK 16
#define KCHUNK (DIM / SPLITK)   // 1024
#define BK 64

typedef __attribute__((ext_vector_type(8))) short bf16x8;
typedef __attribute__((ext_vector_type(4))) float f32x4;

// LDS swizzle for the state arrays: i + 5*(i>>5)  (injective, <=2-way banks)
#define SW(i) ((i) + 5 * ((i) >> 5))
#define SW_SIZE (DIM + 5 * (DIM / 32))   // 16384 + 2560 = 18944

// ---------------------------------------------------------------- kernel A
// params = x @ w_pre^T + b_pre ; v[b][q] = (cos(th/2), 0, cos(phi)sin, sin(phi)sin)
__global__ __launch_bounds__(256) void k_pre(const float* __restrict__ x,
                                             const float* __restrict__ w_pre,
                                             const float* __restrict__ b_pre,
                                             float* __restrict__ v_buf) {
    int b = blockIdx.x;
    int t = threadIdx.x;
    __shared__ float red[28][4];

    float4 xs = ((const float4*)(x + (size_t)b * NH))[t];
    float acc[28];
#pragma unroll
    for (int j = 0; j < 28; j++) {
        float4 w = ((const float4*)(w_pre + (size_t)j * NH))[t];
        acc[j] = xs.x * w.x + xs.y * w.y + xs.z * w.z + xs.w * w.w;
    }
    int lane = t & 63, wv = t >> 6;
#pragma unroll
    for (int j = 0; j < 28; j++) {
        float a = acc[j];
#pragma unroll
        for (int o = 32; o > 0; o >>= 1) a += __shfl_down(a, o);
        if (lane == 0) red[j][wv] = a;
    }
    __syncthreads();
    if (t < NQ) {
        float p0 = red[2*t][0] + red[2*t][1] + red[2*t][2] + red[2*t][3] + b_pre[2*t];
        float p1 = red[2*t+1][0] + red[2*t+1][1] + red[2*t+1][2] + red[2*t+1][3] + b_pre[2*t+1];
        float c = cosf(p0 * 0.5f), s = sinf(p0 * 0.5f);
        float cp = cosf(p1), sp = sinf(p1);
        ((float4*)v_buf)[b * NQ + t] = make_float4(c, 0.f, cp * s, sp * s);
    }
}

// ---------------------------------------------------------------- kernel B
// Gram-Schmidt QR (double) -> Q with positive-real diag(R) == make_unitary(M)
template <int N>
__device__ void gs_qr(const float* Mre, const float* Mim, float* Uout) {
    double qre[N][N], qim[N][N];   // [col][row]
#pragma unroll
    for (int j = 0; j < N; j++) {
        double vr[N], vi[N];
#pragma unroll
        for (int r = 0; r < N; r++) { vr[r] = (double)Mre[r * N + j]; vi[r] = (double)Mim[r * N + j]; }
#pragma unroll
        for (int i = 0; i < N; i++) {
            if (i < j) {
                double rr = 0.0, ri = 0.0;
#pragma unroll
                for (int r = 0; r < N; r++) {
                    rr += qre[i][r] * vr[r] + qim[i][r] * vi[r];
                    ri += qre[i][r] * vi[r] - qim[i][r] * vr[r];
                }
#pragma unroll
                for (int r = 0; r < N; r++) {
                    vr[r] -= rr * qre[i][r] - ri * qim[i][r];
                    vi[r] -= rr * qim[i][r] + ri * qre[i][r];
                }
            }
        }
        double nn = 0.0;
#pragma unroll
        for (int r = 0; r < N; r++) nn += vr[r] * vr[r] + vi[r] * vi[r];
        double inv = 1.0 / sqrt(nn);
#pragma unroll
        for (int r = 0; r < N; r++) { qre[j][r] = vr[r] * inv; qim[j][r] = vi[r] * inv; }
    }
#pragma unroll
    for (int r = 0; r < N; r++)
#pragma unroll
        for (int j = 0; j < N; j++) {
            Uout[(r * N + j) * 2]     = (float)qre[j][r];
            Uout[(r * N + j) * 2 + 1] = (float)qim[j][r];
        }
}

__global__ void k_qr(const float* __restrict__ sq_re, const float* __restrict__ sq_im,
                     const float* __restrict__ ent_re, const float* __restrict__ ent_im,
                     float* __restrict__ sqU, float* __restrict__ entU) {
    int t = threadIdx.x;
    if (t < NQ) {
        gs_qr<2>(sq_re + t * 4, sq_im + t * 4, sqU + t * 8);
    } else if (t < NQ + (NQ - 1)) {
        int e = t - NQ;
        gs_qr<4>(ent_re + e * 16, ent_im + e * 16, entU + e * 32);
    }
}

// ---------------------------------------------------------------- kernel C
// Per batch row: build state = prod_q (U_q v_q) directly (1q gates fused into
// the product), apply 13 two-qubit gates in LDS, write probs (bf16).
extern __shared__ float smem[];
__global__ __launch_bounds__(1024) void k_state(const float* __restrict__ v_buf,
                                                const float* __restrict__ sqU,
                                                const float* __restrict__ entU,
                                                __hip_bfloat16* __restrict__ probs) {
    const int b = blockIdx.x, t = threadIdx.x;
    float* sre  = smem;                       // SW_SIZE
    float* simg = smem + SW_SIZE;             // SW_SIZE
    float* wloc = smem + 2 * SW_SIZE;         // 14*4
    float* g2   = wloc + NQ * 4;              // 13*32
    float* hi   = g2 + (NQ - 1) * 32;         // 16*2

    if (t < (NQ - 1) * 32) g2[t] = entU[t];
    if (t < NQ) {
        // w_q = U_q v_q  (fused single-qubit gates)
        float4 v = ((const float4*)v_buf)[b * NQ + t];
        const float* u = sqU + t * 8;
        float w0r = u[0]*v.x - u[1]*v.y + u[2]*v.z - u[3]*v.w;
        float w0i = u[0]*v.y + u[1]*v.x + u[2]*v.w + u[3]*v.z;
        float w1r = u[4]*v.x - u[5]*v.y + u[6]*v.z - u[7]*v.w;
        float w1i = u[4]*v.y + u[5]*v.x + u[6]*v.w + u[7]*v.z;
        wloc[t*4+0] = w0r; wloc[t*4+1] = w0i; wloc[t*4+2] = w1r; wloc[t*4+3] = w1i;
    }
    __syncthreads();
    if (t < 16) {   // product over qubits 10..13 (index bits 10..13 = k)
        float hr = 1.f, hii = 0.f;
#pragma unroll
        for (int q = 10; q < 14; q++) {
            int bit = (t >> (q - 10)) & 1;
            float br = wloc[q*4 + 2*bit], bi = wloc[q*4 + 2*bit + 1];
            float nr = hr*br - hii*bi, ni = hr*bi + hii*br;
            hr = nr; hii = ni;
        }
        hi[2*t] = hr; hi[2*t+1] = hii;
    }
    __syncthreads();
    {   // product over qubits 0..9 (index bits 0..9 = t)
        float lr = 1.f, li = 0.f;
#pragma unroll
        for (int q = 0; q < 10; q++) {
            int bit = (t >> q) & 1;
            float br = wloc[q*4 + 2*bit], bi = wloc[q*4 + 2*bit + 1];
            float nr = lr*br - li*bi, ni = lr*bi + li*br;
            lr = nr; li = ni;
        }
#pragma unroll
        for (int k = 0; k < 16; k++) {
            int idx = k * 1024 + t;
            float hr = hi[2*k], hii = hi[2*k+1];
            sre[SW(idx)]  = lr*hr - li*hii;
            simg[SW(idx)] = lr*hii + li*hr;
        }
    }
    __syncthreads();

    // 13 two-qubit gates on (q, q+1); matrix row = 2*bit_{q+1} + bit_q,
    // amplitude offset of matrix index m is base + (m<<q).
    for (int e = 0; e < NQ - 1; e++) {
        float gr[4][4], gi[4][4];
#pragma unroll
        for (int m = 0; m < 16; m++) {
            gr[m >> 2][m & 3] = g2[e*32 + 2*m];
            gi[m >> 2][m & 3] = g2[e*32 + 2*m + 1];
        }
        const int q = e, mask = (1 << q) - 1;
#pragma unroll
        for (int k = 0; k < 4; k++) {
            int g = k * 1024 + t;
            int base = ((g & ~mask) << 2) | (g & mask);
            int ia[4];
#pragma unroll
            for (int m = 0; m < 4; m++) ia[m] = SW(base + (m << q));
            float ar[4], ai[4];
#pragma unroll
            for (int m = 0; m < 4; m++) { ar[m] = sre[ia[m]]; ai[m] = simg[ia[m]]; }
            float orr[4], oii[4];
#pragma unroll
            for (int r = 0; r < 4; r++) {
                float nr = 0.f, ni = 0.f;
#pragma unroll
                for (int c = 0; c < 4; c++) {
                    nr += gr[r][c] * ar[c] - gi[r][c] * ai[c];
                    ni += gr[r][c] * ai[c] + gi[r][c] * ar[c];
                }
                orr[r] = nr; oii[r] = ni;
            }
#pragma unroll
            for (int r = 0; r < 4; r++) { sre[ia[r]] = orr[r]; simg[ia[r]] = oii[r]; }
        }
        __syncthreads();
    }

#pragma unroll
    for (int k = 0; k < 16; k++) {
        int idx = k * 1024 + t;
        float r = sre[SW(idx)], i2 = simg[SW(idx)];
        probs[(size_t)b * DIM + idx] = __float2bfloat16(r * r + i2 * i2);
    }
}

// ---------------------------------------------------------------- kernel D
// bf16 MFMA GEMM: part[z] += probs[bf16] @ w_post^T (B f32 -> bf16 in staging)
// 128x128 tile, BK=64, 8 waves (2x4), wave tile 64x32, split-K=16.
__global__ __launch_bounds__(512) void k_gemm_mfma(const ushort* __restrict__ A,
                                                   const float* __restrict__ Bw,
                                                   float* __restrict__ part) {
    __shared__ ushort As[128 * 64];
    __shared__ ushort Bs[128 * 64];
    const int t = threadIdx.x;
    const int l = t & 63, wid = t >> 6;
    const int wr = wid >> 2, wc = wid & 3;          // 2 x 4 waves
    const int bm0 = blockIdx.x * 128;
    const int hn0 = blockIdx.y * 128;
    const int k0  = blockIdx.z * KCHUNK;

    f32x4 acc[4][2];
#pragma unroll
    for (int m = 0; m < 4; m++)
#pragma unroll
        for (int n = 0; n < 2; n++) acc[m][n] = (f32x4){0.f, 0.f, 0.f, 0.f};

    const int srow = t >> 3;            // 0..63 (B staging row within issue)
    const int scol = (t & 7) * 8;       // B staging col (elems)
    const int alr  = l >> 3;            // lane row within wave's 8-row chunk
    const int alc  = (l & 7) * 8;       // lane col (elems)

    for (int kc = 0; kc < KCHUNK; kc += BK) {
        const int kbase = k0 + kc;
        // ---- A: bf16 via global_load_lds (16B/lane), 2 issues x 64 rows
#pragma unroll
        for (int i = 0; i < 2; i++) {
            const int r0 = i * 64 + wid * 8;        // wave-uniform row base
            const ushort* gsrc = A + (size_t)(bm0 + r0 + alr) * DIM + kbase + alc;
            __builtin_amdgcn_global_load_lds(
                (const __attribute__((address_space(1))) unsigned int*)gsrc,
                (__attribute__((address_space(3))) unsigned int*)&As[r0 * 64],
                16, 0, 0);
        }
        // ---- B: f32 load -> bf16 cvt -> ds_write_b128, 2 issues x 64 rows
#pragma unroll
        for (int i = 0; i < 2; i++) {
            const int r = i * 64 + srow;
            const float* bsrc = Bw + (size_t)(hn0 + r) * DIM + kbase + scol;
            float4 b0 = *(const float4*)(bsrc);
            float4 b1 = *(const float4*)(bsrc + 4);
            union { ushort u[8]; bf16x8 v; } pk;
            __hip_bfloat16 h;
            h = __float2bfloat16(b0.x); pk.u[0] = *(ushort*)&h;
            h = __float2bfloat16(b0.y); pk.u[1] = *(ushort*)&h;
            h = __float2bfloat16(b0.z); pk.u[2] = *(ushort*)&h;
            h = __float2bfloat16(b0.w); pk.u[3] = *(ushort*)&h;
            h = __float2bfloat16(b1.x); pk.u[4] = *(ushort*)&h;
            h = __float2bfloat16(b1.y); pk.u[5] = *(ushort*)&h;
            h = __float2bfloat16(b1.z); pk.u[6] = *(ushort*)&h;
            h = __float2bfloat16(b1.w); pk.u[7] = *(ushort*)&h;
            *(bf16x8*)&Bs[r * 64 + scol] = pk.v;
        }
        __syncthreads();   // drains vmcnt (global_load_lds) + lgkmcnt (ds_write)
        // ---- compute: 2 k-steps of 32, 16 MFMAs per wave per iter
#pragma unroll
        for (int kk = 0; kk < 2; kk++) {
            const int kcol = kk * 32 + (l >> 4) * 8;
            bf16x8 a[4], b[2];
#pragma unroll
            for (int m = 0; m < 4; m++)
                a[m] = *(const bf16x8*)&As[(wr * 64 + m * 16 + (l & 15)) * 64 + kcol];
#pragma unroll
            for (int n = 0; n < 2; n++)
                b[n] = *(const bf16x8*)&Bs[(wc * 32 + n * 16 + (l & 15)) * 64 + kcol];
#pragma unroll
            for (int m = 0; m < 4; m++)
#pragma unroll
                for (int n = 0; n < 2; n++)
                    acc[m][n] = __builtin_amdgcn_mfma_f32_16x16x32_bf16(
                        a[m], b[n], acc[m][n], 0, 0, 0);
        }
        __syncthreads();
    }
    // ---- write f32 partials; C/D layout: col = lane&15, row = (lane>>4)*4 + j
    float* dst = part + (size_t)blockIdx.z * (NB * NH);
#pragma unroll
    for (int m = 0; m < 4; m++) {
        const int row = bm0 + wr * 64 + m * 16 + (l >> 4) * 4;
#pragma unroll
        for (int n = 0; n < 2; n++) {
            const int col = hn0 + wc * 32 + n * 16 + (l & 15);
#pragma unroll
            for (int j = 0; j < 4; j++)
                dst[(size_t)(row + j) * NH + col] = acc[m][n][j];
        }
    }
}

__global__ __launch_bounds__(256) void k_reduce(const float* __restrict__ part,
                                                const float* __restrict__ b_post,
                                                float* __restrict__ out) {
    int i = blockIdx.x * 256 + threadIdx.x;   // 0..262143
    float s = b_post[i & (NH - 1)];
#pragma unroll
    for (int z = 0; z < SPLITK; z++) s += part[(size_t)z * (NB * NH) + i];
    out[i] = s;
}

// ---------------------------------------------------------------- launch
extern "C" void kernel_launch(void* const* d_in, const int* in_sizes, int n_in,
                              void* d_out, int out_size, void* d_ws, size_t ws_size,
                              hipStream_t stream) {
    const float* x      = (const float*)d_in[0];
    const float* w_pre  = (const float*)d_in[1];
    const float* b_pre  = (const float*)d_in[2];
    const float* w_post = (const float*)d_in[3];
    const float* b_post = (const float*)d_in[4];
    const float* sq_re  = (const float*)d_in[5];
    const float* sq_im  = (const float*)d_in[6];
    const float* ent_re = (const float*)d_in[7];
    const float* ent_im = (const float*)d_in[8];
    float* out = (float*)d_out;
    char* ws   = (char*)d_ws;

    // byte layout (total 25,225,280 B == round-2 proven footprint)
    float* v_buf         = (float*)(ws);                    // 57,344 B
    float* sqU           = (float*)(ws + 57344);            // 448 B
    float* entU          = (float*)(ws + 57792);            // 1,664 B
    __hip_bfloat16* probs = (__hip_bfloat16*)(ws + 59456);  // 8,388,608 B
    float* part          = (float*)(ws + 8448064);          // 16,777,216 B

    k_pre<<<NB, 256, 0, stream>>>(x, w_pre, b_pre, v_buf);
    k_qr<<<1, 64, 0, stream>>>(sq_re, sq_im, ent_re, ent_im, sqU, entU);

    const int smem_bytes = (2 * SW_SIZE + NQ * 4 + (NQ - 1) * 32 + 32) * 4;
    (void)hipFuncSetAttribute((const void*)k_state,
                              hipFuncAttributeMaxDynamicSharedMemorySize, smem_bytes);
    k_state<<<NB, 1024, smem_bytes, stream>>>(v_buf, sqU, entU, probs);

    k_gemm_mfma<<<dim3(2, 8, SPLITK), 512, 0, stream>>>((const ushort*)probs, w_post, part);
    k_reduce<<<(NB * NH) / 256, 256, 0, stream>>>(part, b_post, out);
}